// Round 2
// baseline (375.272 us; speedup 1.0000x reference)
//
#include <hip/hip_runtime.h>

#define EPS 1e-8f

using f32x4 = __attribute__((ext_vector_type(4))) float;

// B=4, C=128, H=W=256, HW=65536, mask 128x128 per batch (nearest-upsample 2x2)
// Phase 1: partial moment sums. grid = B*C*4 splits, 256 threads.
// stats[(bc*4+s)*12 + j]:
//  j: 0 Σx1 m   1 Σx1 m³   2 Σx1² m⁴   3..5 same for x2
//     6 Σx1 om  7 Σx1 om³  8 Σx1² om⁴  9..11 same for x2
__global__ __launch_bounds__(256) void k_stats(
    const float* __restrict__ x1,
    const float* __restrict__ x2,
    const float* __restrict__ mask,
    float* __restrict__ stats)
{
    int blk = blockIdx.x;          // [0, 2048)
    int s   = blk & 3;
    int bc  = blk >> 2;            // b*128 + c
    int b   = bc >> 7;
    int tid = threadIdx.x;

    const float* xp1 = x1 + (size_t)bc * 65536 + s * 16384;
    const float* xp2 = x2 + (size_t)bc * 65536 + s * 16384;
    const float* mp  = mask + b * 16384;

    float a[12];
#pragma unroll
    for (int j = 0; j < 12; ++j) a[j] = 0.f;

    int base0 = s * 16384;
    for (int it = 0; it < 8; ++it) {
        int off = it * 2048 + tid * 8;      // within 16384-chunk
        int gi  = base0 + off;              // within 65536-plane
        int h = gi >> 8;
        int w = gi & 255;
        const f32x4 v1a = *(const f32x4*)(xp1 + off);
        const f32x4 v1b = *(const f32x4*)(xp1 + off + 4);
        const f32x4 v2a = *(const f32x4*)(xp2 + off);
        const f32x4 v2b = *(const f32x4*)(xp2 + off + 4);
        const f32x4 mv  = *(const f32x4*)(mp + (h >> 1) * 128 + (w >> 1));
#pragma unroll
        for (int j = 0; j < 8; ++j) {
            float m  = mv[j >> 1];
            float om = 1.f - m;
            float m2 = m * m, om2 = om * om;
            float f1 = (j < 4) ? v1a[j & 3] : v1b[j & 3];
            float f2 = (j < 4) ? v2a[j & 3] : v2b[j & 3];
            float p1 = f1 * m2,  p2 = f2 * m2;
            a[0] += f1 * m;  a[1] += p1 * m;  a[2] += p1 * p1;
            a[3] += f2 * m;  a[4] += p2 * m;  a[5] += p2 * p2;
            float q1 = f1 * om2, q2 = f2 * om2;
            a[6] += f1 * om; a[7] += q1 * om; a[8] += q1 * q1;
            a[9] += f2 * om; a[10]+= q2 * om; a[11]+= q2 * q2;
        }
    }
#pragma unroll
    for (int j = 0; j < 12; ++j)
#pragma unroll
        for (int d = 32; d > 0; d >>= 1)
            a[j] += __shfl_down(a[j], d, 64);

    __shared__ float red[4][12];
    int wv = tid >> 6, ln = tid & 63;
    if (ln == 0) {
#pragma unroll
        for (int j = 0; j < 12; ++j) red[wv][j] = a[j];
    }
    __syncthreads();
    if (tid < 12) {
        float v = red[0][tid] + red[1][tid] + red[2][tid] + red[3][tid];
        stats[(size_t)blk * 12 + tid] = v;
    }
}

// Phase 2: per-batch stats + 4 small matvecs. grid = B, 256 threads.
// derived[(b*128+c)*8 + {0..7}] = {mean_in, inv_in, mean_out, inv_out,
//                                  ada_in_mean, ada_in_var, ada_out_mean, ada_out_var}
__global__ __launch_bounds__(256) void k_mod(
    const float* __restrict__ mask,
    const float* __restrict__ w_in_mean,
    const float* __restrict__ w_in_var,
    const float* __restrict__ w_out_mean,
    const float* __restrict__ w_out_var,
    const float* __restrict__ stats,
    float* __restrict__ derived)
{
    int b   = blockIdx.x;
    int tid = threadIdx.x;

    // mask sums over half-res grid (upsampled sums are 4x)
    const float* mp = mask + b * 16384;
    float sm = 0.f, sm2 = 0.f;
    for (int it = 0; it < 16; ++it) {
        const f32x4 mv = *(const f32x4*)(mp + (it * 256 + tid) * 4);
#pragma unroll
        for (int j = 0; j < 4; ++j) { float m = mv[j]; sm += m; sm2 += m * m; }
    }
#pragma unroll
    for (int d = 32; d > 0; d >>= 1) {
        sm  += __shfl_down(sm, d, 64);
        sm2 += __shfl_down(sm2, d, 64);
    }
    __shared__ float rr[8];
    __shared__ float SMs, SM2s;
    int wv = tid >> 6, ln = tid & 63;
    if (ln == 0) { rr[wv] = sm; rr[4 + wv] = sm2; }
    __syncthreads();
    if (tid == 0) {
        SMs  = 4.f * (rr[0] + rr[1] + rr[2] + rr[3]);
        SM2s = 4.f * (rr[4] + rr[5] + rr[6] + rr[7]);
    }
    __syncthreads();
    float SM = SMs, SM2 = SM2s;
    float n_in  = SM + EPS;
    float n_out = 65536.f - SM + EPS;
    float SOM2  = 65536.f - 2.f * SM + SM2;

    __shared__ float vin_mean[256], vin_var[256], vout_mean[256], vout_var[256];

    if (tid < 128) {
        int c = tid;
        const float* st = stats + (size_t)(b * 128 + c) * 4 * 12;
        float s[12];
#pragma unroll
        for (int j = 0; j < 12; ++j) s[j] = st[j] + st[12 + j] + st[24 + j] + st[36 + j];
        float mi1 = s[0] / n_in;
        float vi1 = fmaxf((s[2] - 2.f * mi1 * s[1] + mi1 * mi1 * SM2) / n_in, 0.f);
        float mi2 = s[3] / n_in;
        float vi2 = fmaxf((s[5] - 2.f * mi2 * s[4] + mi2 * mi2 * SM2) / n_in, 0.f);
        float mo1 = s[6] / n_out;
        float vo1 = fmaxf((s[8] - 2.f * mo1 * s[7] + mo1 * mo1 * SOM2) / n_out, 0.f);
        float mo2 = s[9] / n_out;
        float vo2 = fmaxf((s[11] - 2.f * mo2 * s[10] + mo2 * mo2 * SOM2) / n_out, 0.f);
        vin_mean[c] = mi1;  vin_mean[128 + c] = mi2;
        vin_var[c]  = vi1;  vin_var[128 + c]  = vi2;
        vout_mean[c] = mo1; vout_mean[128 + c] = mo2;
        vout_var[c]  = vo1; vout_var[128 + c]  = vo2;
        float* d = derived + (size_t)(b * 128 + c) * 8;
        d[0] = mi1; d[1] = rsqrtf(vi1 + EPS);
        d[2] = mo1; d[3] = rsqrtf(vo1 + EPS);
    }
    __syncthreads();

    for (int t = tid; t < 512; t += 256) {
        int mat = t >> 7, row = t & 127;
        const float* wp;
        const float* vec;
        if (mat == 0)      { wp = w_in_mean;  vec = vin_mean; }
        else if (mat == 1) { wp = w_in_var;   vec = vin_var; }
        else if (mat == 2) { wp = w_out_mean; vec = vout_mean; }
        else               { wp = w_out_var;  vec = vout_var; }
        wp += row * 256;
        float acc = 0.f;
        for (int k = 0; k < 256; k += 4) {
            f32x4 wv4 = *(const f32x4*)(wp + k);
#pragma unroll
            for (int j = 0; j < 4; ++j) acc += wv4[j] * vec[k + j];
        }
        derived[(size_t)(b * 128 + row) * 8 + 4 + mat] = acc;
    }
}

// Phase 3: elementwise apply. grid = B*C*32, 256 threads, 8 els/thread.
__global__ __launch_bounds__(256) void k_apply(
    const float* __restrict__ x1,
    const float* __restrict__ mask,
    const float* __restrict__ derived,
    float* __restrict__ out)
{
    int blk   = blockIdx.x;
    int bc    = blk >> 5;
    int chunk = blk & 31;
    int b     = bc >> 7;
    const float* d = derived + (size_t)bc * 8;
    float mean_in = d[0], inv_in = d[1], mean_out = d[2], inv_out = d[3];
    float am_in = d[4], av_in = d[5], am_out = d[6], av_out = d[7];
    float ci1 = inv_in * av_in;
    float ci0 = am_in - mean_in * ci1;
    float co1 = inv_out * av_out;
    float co0 = am_out - mean_out * co1;

    int tid = threadIdx.x;
    int off = chunk * 2048 + tid * 8;
    int h = off >> 8, w = off & 255;
    const f32x4 xa = *(const f32x4*)(x1 + (size_t)bc * 65536 + off);
    const f32x4 xb = *(const f32x4*)(x1 + (size_t)bc * 65536 + off + 4);
    const f32x4 mv = *(const f32x4*)(mask + b * 16384 + (h >> 1) * 128 + (w >> 1));
    f32x4 oa, ob;
#pragma unroll
    for (int j = 0; j < 8; ++j) {
        float m  = mv[j >> 1];
        float om = 1.f - m;
        float x  = (j < 4) ? xa[j & 3] : xb[j & 3];
        float r  = x * (m * m * ci1 + om * om * co1) + ci0 * m + co0 * om;
        if (j < 4) oa[j & 3] = r; else ob[j & 3] = r;
    }
    *(f32x4*)(out + (size_t)bc * 65536 + off)     = oa;
    *(f32x4*)(out + (size_t)bc * 65536 + off + 4) = ob;
}

extern "C" void kernel_launch(void* const* d_in, const int* in_sizes, int n_in,
                              void* d_out, int out_size, void* d_ws, size_t ws_size,
                              hipStream_t stream) {
    const float* x1        = (const float*)d_in[0];
    const float* x2        = (const float*)d_in[1];
    const float* mask      = (const float*)d_in[2];
    const float* w_in_mean = (const float*)d_in[3];
    const float* w_in_var  = (const float*)d_in[4];
    const float* w_out_mean= (const float*)d_in[5];
    const float* w_out_var = (const float*)d_in[6];

    float* stats   = (float*)d_ws;              // 2048 * 12 floats
    float* derived = stats + 2048 * 12;         // 512 * 8 floats
    float* out = (float*)d_out;

    k_stats<<<4 * 128 * 4, 256, 0, stream>>>(x1, x2, mask, stats);
    k_mod<<<4, 256, 0, stream>>>(mask, w_in_mean, w_in_var, w_out_mean, w_out_var,
                                 stats, derived);
    k_apply<<<4 * 128 * 32, 256, 0, stream>>>(x1, mask, derived, out);
}

// Round 3
// 374.587 us; speedup vs baseline: 1.0018x; 1.0018x over previous
//
#include <hip/hip_runtime.h>

#define EPS 1e-8f

using f32x4 = __attribute__((ext_vector_type(4))) float;

// B=4, C=128, H=W=256, HW=65536, mask 128x128 per batch (nearest-upsample 2x2)
// Phase 1: partial moment sums, software-pipelined. grid = 512*2, 256 threads.
// stats[(bc*2+s)*12 + j]:
//  j: 0 Σx1 m   1 Σx1 m³   2 Σx1² m⁴   3..5 same for x2
//     6 Σx1 om  7 Σx1 om³  8 Σx1² om⁴  9..11 same for x2
__global__ __launch_bounds__(256) void k_stats(
    const float* __restrict__ x1,
    const float* __restrict__ x2,
    const float* __restrict__ mask,
    float* __restrict__ stats)
{
    int blk = blockIdx.x;          // [0, 1024)
    int s   = blk & 1;
    int bc  = blk >> 1;            // b*128 + c
    int b   = bc >> 7;
    int tid = threadIdx.x;

    const size_t poff = (size_t)bc * 65536 + (size_t)s * 32768;
    const float* xp1 = x1 + poff;
    const float* xp2 = x2 + poff;
    const float* mp  = mask + b * 16384;
    const int gi0 = s * 32768 + tid * 8;   // within-plane index of this thread's group 0

    float a[12];
#pragma unroll
    for (int j = 0; j < 12; ++j) a[j] = 0.f;

    // current-group registers (prefetched)
    int off0 = tid * 8;
    f32x4 c1a = *(const f32x4*)(xp1 + off0);
    f32x4 c1b = *(const f32x4*)(xp1 + off0 + 4);
    f32x4 c2a = *(const f32x4*)(xp2 + off0);
    f32x4 c2b = *(const f32x4*)(xp2 + off0 + 4);
    int h0 = gi0 >> 8, w0 = gi0 & 255;
    f32x4 cm = *(const f32x4*)(mp + (h0 >> 1) * 128 + (w0 >> 1));

    for (int g = 0; g < 16; ++g) {
        f32x4 n1a, n1b, n2a, n2b, nm;
        if (g < 15) {
            int off = (g + 1) * 2048 + tid * 8;
            int gi  = gi0 + (g + 1) * 2048;
            int h = gi >> 8, w = gi & 255;
            n1a = *(const f32x4*)(xp1 + off);
            n1b = *(const f32x4*)(xp1 + off + 4);
            n2a = *(const f32x4*)(xp2 + off);
            n2b = *(const f32x4*)(xp2 + off + 4);
            nm  = *(const f32x4*)(mp + (h >> 1) * 128 + (w >> 1));
        }
#pragma unroll
        for (int j = 0; j < 8; ++j) {
            float m  = cm[j >> 1];
            float om = 1.f - m;
            float m2 = m * m, om2 = om * om;
            float f1 = (j < 4) ? c1a[j & 3] : c1b[j & 3];
            float f2 = (j < 4) ? c2a[j & 3] : c2b[j & 3];
            float p1 = f1 * m2,  p2 = f2 * m2;
            a[0] += f1 * m;  a[1] += p1 * m;  a[2] += p1 * p1;
            a[3] += f2 * m;  a[4] += p2 * m;  a[5] += p2 * p2;
            float q1 = f1 * om2, q2 = f2 * om2;
            a[6] += f1 * om; a[7] += q1 * om; a[8] += q1 * q1;
            a[9] += f2 * om; a[10]+= q2 * om; a[11]+= q2 * q2;
        }
        c1a = n1a; c1b = n1b; c2a = n2a; c2b = n2b; cm = nm;
    }

#pragma unroll
    for (int j = 0; j < 12; ++j)
#pragma unroll
        for (int d = 32; d > 0; d >>= 1)
            a[j] += __shfl_down(a[j], d, 64);

    __shared__ float red[4][12];
    int wv = tid >> 6, ln = tid & 63;
    if (ln == 0) {
#pragma unroll
        for (int j = 0; j < 12; ++j) red[wv][j] = a[j];
    }
    __syncthreads();
    if (tid < 12) {
        float v = red[0][tid] + red[1][tid] + red[2][tid] + red[3][tid];
        stats[(size_t)blk * 12 + tid] = v;
    }
}

// Phase 2: per-batch stats + 4 small matvecs. grid = B, 256 threads.
// derived[(b*128+c)*8 + {0..7}] = {mean_in, inv_in, mean_out, inv_out,
//                                  ada_in_mean, ada_in_var, ada_out_mean, ada_out_var}
__global__ __launch_bounds__(256) void k_mod(
    const float* __restrict__ mask,
    const float* __restrict__ w_in_mean,
    const float* __restrict__ w_in_var,
    const float* __restrict__ w_out_mean,
    const float* __restrict__ w_out_var,
    const float* __restrict__ stats,
    float* __restrict__ derived)
{
    int b   = blockIdx.x;
    int tid = threadIdx.x;

    // mask sums over half-res grid (upsampled sums are 4x)
    const float* mp = mask + b * 16384;
    float sm = 0.f, sm2 = 0.f;
    for (int it = 0; it < 16; ++it) {
        const f32x4 mv = *(const f32x4*)(mp + (it * 256 + tid) * 4);
#pragma unroll
        for (int j = 0; j < 4; ++j) { float m = mv[j]; sm += m; sm2 += m * m; }
    }
#pragma unroll
    for (int d = 32; d > 0; d >>= 1) {
        sm  += __shfl_down(sm, d, 64);
        sm2 += __shfl_down(sm2, d, 64);
    }
    __shared__ float rr[8];
    __shared__ float SMs, SM2s;
    int wv = tid >> 6, ln = tid & 63;
    if (ln == 0) { rr[wv] = sm; rr[4 + wv] = sm2; }
    __syncthreads();
    if (tid == 0) {
        SMs  = 4.f * (rr[0] + rr[1] + rr[2] + rr[3]);
        SM2s = 4.f * (rr[4] + rr[5] + rr[6] + rr[7]);
    }
    __syncthreads();
    float SM = SMs, SM2 = SM2s;
    float n_in  = SM + EPS;
    float n_out = 65536.f - SM + EPS;
    float SOM2  = 65536.f - 2.f * SM + SM2;

    __shared__ float vin_mean[256], vin_var[256], vout_mean[256], vout_var[256];

    if (tid < 128) {
        int c = tid;
        const float* st = stats + (size_t)(b * 128 + c) * 2 * 12;
        float s[12];
#pragma unroll
        for (int j = 0; j < 12; ++j) s[j] = st[j] + st[12 + j];
        float mi1 = s[0] / n_in;
        float vi1 = fmaxf((s[2] - 2.f * mi1 * s[1] + mi1 * mi1 * SM2) / n_in, 0.f);
        float mi2 = s[3] / n_in;
        float vi2 = fmaxf((s[5] - 2.f * mi2 * s[4] + mi2 * mi2 * SM2) / n_in, 0.f);
        float mo1 = s[6] / n_out;
        float vo1 = fmaxf((s[8] - 2.f * mo1 * s[7] + mo1 * mo1 * SOM2) / n_out, 0.f);
        float mo2 = s[9] / n_out;
        float vo2 = fmaxf((s[11] - 2.f * mo2 * s[10] + mo2 * mo2 * SOM2) / n_out, 0.f);
        vin_mean[c] = mi1;  vin_mean[128 + c] = mi2;
        vin_var[c]  = vi1;  vin_var[128 + c]  = vi2;
        vout_mean[c] = mo1; vout_mean[128 + c] = mo2;
        vout_var[c]  = vo1; vout_var[128 + c]  = vo2;
        float* d = derived + (size_t)(b * 128 + c) * 8;
        d[0] = mi1; d[1] = rsqrtf(vi1 + EPS);
        d[2] = mo1; d[3] = rsqrtf(vo1 + EPS);
    }
    __syncthreads();

    for (int t = tid; t < 512; t += 256) {
        int mat = t >> 7, row = t & 127;
        const float* wp;
        const float* vec;
        if (mat == 0)      { wp = w_in_mean;  vec = vin_mean; }
        else if (mat == 1) { wp = w_in_var;   vec = vin_var; }
        else if (mat == 2) { wp = w_out_mean; vec = vout_mean; }
        else               { wp = w_out_var;  vec = vout_var; }
        wp += row * 256;
        float acc = 0.f;
        for (int k = 0; k < 256; k += 4) {
            f32x4 wv4 = *(const f32x4*)(wp + k);
#pragma unroll
            for (int j = 0; j < 4; ++j) acc += wv4[j] * vec[k + j];
        }
        derived[(size_t)(b * 128 + row) * 8 + 4 + mat] = acc;
    }
}

// Phase 3: elementwise apply, software-pipelined. grid = 512*4, 256 threads,
// 64 els/thread in 8 groups of 8.
__global__ __launch_bounds__(256) void k_apply(
    const float* __restrict__ x1,
    const float* __restrict__ mask,
    const float* __restrict__ derived,
    float* __restrict__ out)
{
    int blk   = blockIdx.x;        // [0, 2048)
    int bc    = blk >> 2;
    int chunk = blk & 3;
    int b     = bc >> 7;
    const float* d = derived + (size_t)bc * 8;
    float mean_in = d[0], inv_in = d[1], mean_out = d[2], inv_out = d[3];
    float am_in = d[4], av_in = d[5], am_out = d[6], av_out = d[7];
    float ci1 = inv_in * av_in;
    float ci0 = am_in - mean_in * ci1;
    float co1 = inv_out * av_out;
    float co0 = am_out - mean_out * co1;

    int tid = threadIdx.x;
    const float* xp = x1 + (size_t)bc * 65536;
    float* op = out + (size_t)bc * 65536;
    const float* mp = mask + b * 16384;
    const int gi0 = chunk * 16384 + tid * 8;

    f32x4 cxa = *(const f32x4*)(xp + gi0);
    f32x4 cxb = *(const f32x4*)(xp + gi0 + 4);
    int h0 = gi0 >> 8, w0 = gi0 & 255;
    f32x4 cm = *(const f32x4*)(mp + (h0 >> 1) * 128 + (w0 >> 1));

    for (int g = 0; g < 8; ++g) {
        f32x4 nxa, nxb, nm;
        if (g < 7) {
            int gi = gi0 + (g + 1) * 2048;
            int h = gi >> 8, w = gi & 255;
            nxa = *(const f32x4*)(xp + gi);
            nxb = *(const f32x4*)(xp + gi + 4);
            nm  = *(const f32x4*)(mp + (h >> 1) * 128 + (w >> 1));
        }
        f32x4 oa, ob;
#pragma unroll
        for (int j = 0; j < 8; ++j) {
            float m  = cm[j >> 1];
            float om = 1.f - m;
            float x  = (j < 4) ? cxa[j & 3] : cxb[j & 3];
            float r  = x * (m * m * ci1 + om * om * co1) + ci0 * m + co0 * om;
            if (j < 4) oa[j & 3] = r; else ob[j & 3] = r;
        }
        int go = gi0 + g * 2048;
        __builtin_nontemporal_store(oa, (f32x4*)(op + go));
        __builtin_nontemporal_store(ob, (f32x4*)(op + go + 4));
        cxa = nxa; cxb = nxb; cm = nm;
    }
}

extern "C" void kernel_launch(void* const* d_in, const int* in_sizes, int n_in,
                              void* d_out, int out_size, void* d_ws, size_t ws_size,
                              hipStream_t stream) {
    const float* x1        = (const float*)d_in[0];
    const float* x2        = (const float*)d_in[1];
    const float* mask      = (const float*)d_in[2];
    const float* w_in_mean = (const float*)d_in[3];
    const float* w_in_var  = (const float*)d_in[4];
    const float* w_out_mean= (const float*)d_in[5];
    const float* w_out_var = (const float*)d_in[6];

    float* stats   = (float*)d_ws;              // 1024 * 12 floats
    float* derived = stats + 1024 * 12;         // 512 * 8 floats
    float* out = (float*)d_out;

    k_stats<<<512 * 2, 256, 0, stream>>>(x1, x2, mask, stats);
    k_mod<<<4, 256, 0, stream>>>(mask, w_in_mean, w_in_var, w_out_mean, w_out_var,
                                 stats, derived);
    k_apply<<<512 * 4, 256, 0, stream>>>(x1, mask, derived, out);
}